// Round 1
// baseline (389.415 us; speedup 1.0000x reference)
//
#include <hip/hip_runtime.h>
#include <hip/hip_bf16.h>

// ContrastiveLoss (SimCLR InfoNCE): N=8192, D=1024, T=0.1
// nll[i] = -logit[i, (i+N/2)%N] + logsumexp_j(logit[i,j]), diag masked out
// logit = cos_sim / T; out = mean(nll)
//
// Key identities used:
//  - logit[i,j] = zn_i . zn_j where zn_i = z_i / (||z_i|| * sqrt(T))
//  - logit in [-10, 10]  => logsumexp with FIXED offset 10 (no max tracking);
//    masked diagonal contributes exp(-655040)=0, so just skip it.
//  - cross-block logsumexp combine == atomicAdd of partial sum-exp.

#define N_ROWS 8192
#define DIM    1024
#define BM 128
#define BN 128
#define BK 64
#define TCOUNT 4          // column tiles (of BN) per block
#define LOGIT_MAX 10.0f   // 1/T
#define INV_SQRT_T 3.16227766016838f

typedef __bf16 bf16x8 __attribute__((ext_vector_type(8)));
typedef float floatx4 __attribute__((ext_vector_type(4)));

// ---------------- Kernel 1: row normalize (+ zero sumexp accumulators) ----
__global__ __launch_bounds__(256) void normalize_kernel(
    const float* __restrict__ z, __hip_bfloat16* __restrict__ zn,
    float* __restrict__ sumexp) {
  const int row = blockIdx.x;
  const int tid = threadIdx.x;

  // zero the 8192 sumexp slots using the first 32 blocks (stream-ordered
  // before the fused kernel, so no race)
  if (row < (N_ROWS / 256)) sumexp[row * 256 + tid] = 0.0f;

  const float4 v = ((const float4*)(z + (size_t)row * DIM))[tid];
  float ss = v.x * v.x + v.y * v.y + v.z * v.z + v.w * v.w;
  // wave64 reduce
  #pragma unroll
  for (int off = 32; off > 0; off >>= 1) ss += __shfl_down(ss, off);
  __shared__ float red[4];
  const int wave = tid >> 6, lane = tid & 63;
  if (lane == 0) red[wave] = ss;
  __syncthreads();
  const float tot = red[0] + red[1] + red[2] + red[3];
  const float scale = rsqrtf(tot) * INV_SQRT_T;  // norms ~32 >> eps, eps never binds

  __hip_bfloat16 o[4];
  o[0] = __float2bfloat16(v.x * scale);
  o[1] = __float2bfloat16(v.y * scale);
  o[2] = __float2bfloat16(v.z * scale);
  o[3] = __float2bfloat16(v.w * scale);
  ((uint2*)(zn + (size_t)row * DIM))[tid] = *(const uint2*)o;
}

// ---------------- Kernel 2: fused GEMM + partial logsumexp ----------------
// Block: 256 threads = 4 waves in 2x2 layout over a 128x128 output tile.
// Each wave: 64x64 via 4x4 grid of 16x16x32 bf16 MFMAs.
// LDS tiles 128x64 bf16, 16B-chunk XOR swizzle (chunk c stored at c^(r&7))
// so both staging writes and ds_read_b128 fragment reads are ~conflict-free.
__global__ __launch_bounds__(256) void fused_gemm_lse(
    const __hip_bfloat16* __restrict__ zn,
    float* __restrict__ sumexp, float* __restrict__ pos) {
  __shared__ __hip_bfloat16 sA[BM * BK];
  __shared__ __hip_bfloat16 sB[BN * BK];

  const int tid  = threadIdx.x;
  const int lane = tid & 63;
  const int wave = tid >> 6;
  const int quad = lane >> 4;
  const int l15  = lane & 15;
  const int waveM = wave >> 1;  // 0..1
  const int waveN = wave & 1;   // 0..1
  const int rowBase  = blockIdx.x * BM;
  const int colChunk = blockIdx.y * (BN * TCOUNT);

  float l_acc[4][4];  // [mi][reg] partial sum of exp(s-10) over this block's cols
  #pragma unroll
  for (int i = 0; i < 4; i++)
    #pragma unroll
    for (int j = 0; j < 4; j++) l_acc[i][j] = 0.0f;

  for (int t = 0; t < TCOUNT; ++t) {
    const int colBase = colChunk + t * BN;

    floatx4 acc[4][4];
    #pragma unroll
    for (int mi = 0; mi < 4; mi++)
      #pragma unroll
      for (int ni = 0; ni < 4; ni++) acc[mi][ni] = {0.f, 0.f, 0.f, 0.f};

    for (int kk = 0; kk < DIM; kk += BK) {
      __syncthreads();  // previous iter's LDS reads done
      // stage A and B tiles: 1024 16B-chunks each, 4 per thread
      #pragma unroll
      for (int i = 0; i < 4; i++) {
        const int s = i * 256 + tid;
        const int r = s >> 3;        // tile row 0..127
        const int c = s & 7;         // stored chunk
        const int q = c ^ (r & 7);   // logical k-chunk (swizzle)
        ((uint4*)sA)[s] = *(const uint4*)(zn + (size_t)(rowBase + r) * DIM + kk + q * 8);
        ((uint4*)sB)[s] = *(const uint4*)(zn + (size_t)(colBase + r) * DIM + kk + q * 8);
      }
      __syncthreads();

      #pragma unroll
      for (int ks = 0; ks < 2; ++ks) {   // two K=32 steps per BK=64
        bf16x8 a[4], b[4];
        #pragma unroll
        for (int mi = 0; mi < 4; mi++) {
          const int r = waveM * 64 + mi * 16 + l15;
          const int c = (ks * 4 + quad) ^ (r & 7);
          a[mi] = ((const bf16x8*)sA)[r * 8 + c];
        }
        #pragma unroll
        for (int ni = 0; ni < 4; ni++) {
          const int r = waveN * 64 + ni * 16 + l15;
          const int c = (ks * 4 + quad) ^ (r & 7);
          b[ni] = ((const bf16x8*)sB)[r * 8 + c];
        }
        #pragma unroll
        for (int mi = 0; mi < 4; mi++)
          #pragma unroll
          for (int ni = 0; ni < 4; ni++)
            acc[mi][ni] = __builtin_amdgcn_mfma_f32_16x16x32_bf16(
                a[mi], b[ni], acc[mi][ni], 0, 0, 0);
      }
    }

    // epilogue: C/D layout (16x16): col = lane&15, row = quad*4 + reg  [m89]
    #pragma unroll
    for (int mi = 0; mi < 4; mi++) {
      const int rbase = rowBase + waveM * 64 + mi * 16 + quad * 4;
      #pragma unroll
      for (int r = 0; r < 4; r++) {
        const int grow = rbase + r;
        const int pcol = (grow + N_ROWS / 2) & (N_ROWS - 1);
        #pragma unroll
        for (int ni = 0; ni < 4; ni++) {
          const int gcol = colBase + waveN * 64 + ni * 16 + l15;
          const float s = acc[mi][ni][r];
          if (gcol == grow) continue;          // masked diagonal: exp()=0 exactly
          if (gcol == pcol) pos[grow] = s;     // positive-pair logit (unique writer)
          l_acc[mi][r] += __expf(s - LOGIT_MAX);
        }
      }
    }
  }

  // reduce partial sum-exp across the 16 lanes sharing each row, then one
  // atomicAdd per (row, block)
  #pragma unroll
  for (int mi = 0; mi < 4; mi++)
    #pragma unroll
    for (int r = 0; r < 4; r++) {
      float v = l_acc[mi][r];
      v += __shfl_xor(v, 1);
      v += __shfl_xor(v, 2);
      v += __shfl_xor(v, 4);
      v += __shfl_xor(v, 8);
      if (l15 == 0) {
        const int grow = rowBase + waveM * 64 + mi * 16 + quad * 4 + r;
        atomicAdd(&sumexp[grow], v);
      }
    }
}

// ---------------- Kernel 3: finalize mean NLL -----------------------------
__global__ __launch_bounds__(256) void finalize_kernel(
    const float* __restrict__ sumexp, const float* __restrict__ pos,
    float* __restrict__ out) {
  const int tid = threadIdx.x;
  float local = 0.0f;
  for (int r = tid; r < N_ROWS; r += 256)
    local += -pos[r] + LOGIT_MAX + logf(sumexp[r]);
  #pragma unroll
  for (int off = 32; off > 0; off >>= 1) local += __shfl_down(local, off);
  __shared__ float red[4];
  const int wave = tid >> 6, lane = tid & 63;
  if (lane == 0) red[wave] = local;
  __syncthreads();
  if (tid == 0) out[0] = (red[0] + red[1] + red[2] + red[3]) / (float)N_ROWS;
}

extern "C" void kernel_launch(void* const* d_in, const int* in_sizes, int n_in,
                              void* d_out, int out_size, void* d_ws, size_t ws_size,
                              hipStream_t stream) {
  const float* z = (const float*)d_in[0];
  float* out = (float*)d_out;

  char* ws = (char*)d_ws;
  __hip_bfloat16* zn = (__hip_bfloat16*)ws;                       // 16 MB
  float* sumexp = (float*)(ws + (size_t)N_ROWS * DIM * 2);       // 32 KB
  float* pos    = sumexp + N_ROWS;                               // 32 KB

  normalize_kernel<<<N_ROWS, 256, 0, stream>>>(z, zn, sumexp);
  fused_gemm_lse<<<dim3(N_ROWS / BM, N_ROWS / (BN * TCOUNT)), 256, 0, stream>>>(
      zn, sumexp, pos);
  finalize_kernel<<<1, 256, 0, stream>>>(sumexp, pos, out);
}

// Round 2
// 385.938 us; speedup vs baseline: 1.0090x; 1.0090x over previous
//
#include <hip/hip_runtime.h>
#include <hip/hip_bf16.h>

// ContrastiveLoss (SimCLR InfoNCE): N=8192, D=1024, T=0.1
// nll[i] = -logit[i, (i+N/2)%N] + logsumexp_j(logit[i,j]), diag masked out
// logit = cos_sim / T; out = mean(nll)
//
// Key identities:
//  - logit[i,j] = zn_i . zn_j where zn_i = z_i / (||z_i|| * sqrt(T))
//  - logit in [-10, 10]  => logsumexp with FIXED offset 10 (no max tracking);
//    masked diagonal contributes exp(-655040)=0, so just skip it.
//  - cross-block logsumexp combine == atomicAdd of partial sum-exp.
//
// R2 change: stage A/B tiles with __builtin_amdgcn_global_load_lds width=16
// (async direct-to-LDS, no VGPR round-trip). LDS chunk s is deposited at
// wave-uniform base + lane*16; the XOR swizzle is applied on the GLOBAL
// address side (q = (s&7)^(r&7)), so the fragment-read mapping is unchanged.

#define N_ROWS 8192
#define DIM    1024
#define BM 128
#define BN 128
#define BK 64
#define TCOUNT 4          // column tiles (of BN) per block
#define LOGIT_MAX 10.0f   // 1/T
#define INV_SQRT_T 3.16227766016838f

typedef __bf16 bf16x8 __attribute__((ext_vector_type(8)));
typedef float floatx4 __attribute__((ext_vector_type(4)));

__device__ __forceinline__ void async_copy16(const __hip_bfloat16* g, void* lds) {
  __builtin_amdgcn_global_load_lds(
      (const __attribute__((address_space(1))) void*)g,
      (__attribute__((address_space(3))) void*)lds, 16, 0, 0);
}

// ---------------- Kernel 1: row normalize (+ zero sumexp accumulators) ----
__global__ __launch_bounds__(256) void normalize_kernel(
    const float* __restrict__ z, __hip_bfloat16* __restrict__ zn,
    float* __restrict__ sumexp) {
  const int row = blockIdx.x;
  const int tid = threadIdx.x;

  // zero the 8192 sumexp slots using the first 32 blocks (stream-ordered
  // before the fused kernel, so no race)
  if (row < (N_ROWS / 256)) sumexp[row * 256 + tid] = 0.0f;

  const float4 v = ((const float4*)(z + (size_t)row * DIM))[tid];
  float ss = v.x * v.x + v.y * v.y + v.z * v.z + v.w * v.w;
  // wave64 reduce
  #pragma unroll
  for (int off = 32; off > 0; off >>= 1) ss += __shfl_down(ss, off);
  __shared__ float red[4];
  const int wave = tid >> 6, lane = tid & 63;
  if (lane == 0) red[wave] = ss;
  __syncthreads();
  const float tot = red[0] + red[1] + red[2] + red[3];
  const float scale = rsqrtf(tot) * INV_SQRT_T;  // norms ~32 >> eps, eps never binds

  __hip_bfloat16 o[4];
  o[0] = __float2bfloat16(v.x * scale);
  o[1] = __float2bfloat16(v.y * scale);
  o[2] = __float2bfloat16(v.z * scale);
  o[3] = __float2bfloat16(v.w * scale);
  ((uint2*)(zn + (size_t)row * DIM))[tid] = *(const uint2*)o;
}

// ---------------- Kernel 2: fused GEMM + partial logsumexp ----------------
// Block: 256 threads = 4 waves in 2x2 layout over a 128x128 output tile.
// Each wave: 64x64 via 4x4 grid of 16x16x32 bf16 MFMAs.
// LDS tiles 128x64 bf16, 16B-chunk XOR swizzle (stored chunk c holds logical
// k-chunk c^(r&7)) so ds_read_b128 fragment reads are conflict-free.
__global__ __launch_bounds__(256) void fused_gemm_lse(
    const __hip_bfloat16* __restrict__ zn,
    float* __restrict__ sumexp, float* __restrict__ pos) {
  __shared__ __hip_bfloat16 sA[BM * BK];
  __shared__ __hip_bfloat16 sB[BN * BK];

  const int tid  = threadIdx.x;
  const int lane = tid & 63;
  const int wave = tid >> 6;
  const int quad = lane >> 4;
  const int l15  = lane & 15;
  const int waveM = wave >> 1;  // 0..1
  const int waveN = wave & 1;   // 0..1
  const int rowBase  = blockIdx.x * BM;
  const int colChunk = blockIdx.y * (BN * TCOUNT);

  float l_acc[4][4];  // [mi][reg] partial sum of exp(s-10) over this block's cols
  #pragma unroll
  for (int i = 0; i < 4; i++)
    #pragma unroll
    for (int j = 0; j < 4; j++) l_acc[i][j] = 0.0f;

  for (int t = 0; t < TCOUNT; ++t) {
    const int colBase = colChunk + t * BN;

    floatx4 acc[4][4];
    #pragma unroll
    for (int mi = 0; mi < 4; mi++)
      #pragma unroll
      for (int ni = 0; ni < 4; ni++) acc[mi][ni] = {0.f, 0.f, 0.f, 0.f};

    for (int kk = 0; kk < DIM; kk += BK) {
      __syncthreads();  // previous iter's LDS reads done
      // stage A and B tiles async: 1024 16B-chunks each, 4 waves x 4 iters.
      // Wave-uniform LDS base (sbase*16) + lane*16; per-lane global address
      // carries the XOR swizzle.
      #pragma unroll
      for (int i = 0; i < 4; i++) {
        const int sbase = i * 256 + wave * 64;  // wave-uniform chunk base
        const int s = sbase + lane;             // this lane's chunk
        const int r = s >> 3;                   // tile row 0..127
        const int q = (s & 7) ^ (r & 7);        // logical k-chunk (swizzle)
        const size_t goff = (size_t)r * DIM + kk + q * 8;
        async_copy16(zn + (size_t)rowBase * DIM + goff, (char*)sA + sbase * 16);
        async_copy16(zn + (size_t)colBase * DIM + goff, (char*)sB + sbase * 16);
      }
      __syncthreads();

      #pragma unroll
      for (int ks = 0; ks < 2; ++ks) {   // two K=32 steps per BK=64
        bf16x8 a[4], b[4];
        #pragma unroll
        for (int mi = 0; mi < 4; mi++) {
          const int r = waveM * 64 + mi * 16 + l15;
          const int c = (ks * 4 + quad) ^ (r & 7);
          a[mi] = ((const bf16x8*)sA)[r * 8 + c];
        }
        #pragma unroll
        for (int ni = 0; ni < 4; ni++) {
          const int r = waveN * 64 + ni * 16 + l15;
          const int c = (ks * 4 + quad) ^ (r & 7);
          b[ni] = ((const bf16x8*)sB)[r * 8 + c];
        }
        #pragma unroll
        for (int mi = 0; mi < 4; mi++)
          #pragma unroll
          for (int ni = 0; ni < 4; ni++)
            acc[mi][ni] = __builtin_amdgcn_mfma_f32_16x16x32_bf16(
                a[mi], b[ni], acc[mi][ni], 0, 0, 0);
      }
    }

    // epilogue: C/D layout (16x16): col = lane&15, row = quad*4 + reg  [m89]
    #pragma unroll
    for (int mi = 0; mi < 4; mi++) {
      const int rbase = rowBase + waveM * 64 + mi * 16 + quad * 4;
      #pragma unroll
      for (int r = 0; r < 4; r++) {
        const int grow = rbase + r;
        const int pcol = (grow + N_ROWS / 2) & (N_ROWS - 1);
        #pragma unroll
        for (int ni = 0; ni < 4; ni++) {
          const int gcol = colBase + waveN * 64 + ni * 16 + l15;
          const float s = acc[mi][ni][r];
          if (gcol == grow) continue;          // masked diagonal: exp()=0 exactly
          if (gcol == pcol) pos[grow] = s;     // positive-pair logit (unique writer)
          l_acc[mi][r] += __expf(s - LOGIT_MAX);
        }
      }
    }
  }

  // reduce partial sum-exp across the 16 lanes sharing each row, then one
  // atomicAdd per (row, block)
  #pragma unroll
  for (int mi = 0; mi < 4; mi++)
    #pragma unroll
    for (int r = 0; r < 4; r++) {
      float v = l_acc[mi][r];
      v += __shfl_xor(v, 1);
      v += __shfl_xor(v, 2);
      v += __shfl_xor(v, 4);
      v += __shfl_xor(v, 8);
      if (l15 == 0) {
        const int grow = rowBase + waveM * 64 + mi * 16 + quad * 4 + r;
        atomicAdd(&sumexp[grow], v);
      }
    }
}

// ---------------- Kernel 3: finalize mean NLL -----------------------------
__global__ __launch_bounds__(256) void finalize_kernel(
    const float* __restrict__ sumexp, const float* __restrict__ pos,
    float* __restrict__ out) {
  const int tid = threadIdx.x;
  float local = 0.0f;
  for (int r = tid; r < N_ROWS; r += 256)
    local += -pos[r] + LOGIT_MAX + logf(sumexp[r]);
  #pragma unroll
  for (int off = 32; off > 0; off >>= 1) local += __shfl_down(local, off);
  __shared__ float red[4];
  const int wave = tid >> 6, lane = tid & 63;
  if (lane == 0) red[wave] = local;
  __syncthreads();
  if (tid == 0) out[0] = (red[0] + red[1] + red[2] + red[3]) / (float)N_ROWS;
}

extern "C" void kernel_launch(void* const* d_in, const int* in_sizes, int n_in,
                              void* d_out, int out_size, void* d_ws, size_t ws_size,
                              hipStream_t stream) {
  const float* z = (const float*)d_in[0];
  float* out = (float*)d_out;

  char* ws = (char*)d_ws;
  __hip_bfloat16* zn = (__hip_bfloat16*)ws;                       // 16 MB
  float* sumexp = (float*)(ws + (size_t)N_ROWS * DIM * 2);       // 32 KB
  float* pos    = sumexp + N_ROWS;                               // 32 KB

  normalize_kernel<<<N_ROWS, 256, 0, stream>>>(z, zn, sumexp);
  fused_gemm_lse<<<dim3(N_ROWS / BM, N_ROWS / (BN * TCOUNT)), 256, 0, stream>>>(
      zn, sumexp, pos);
  finalize_kernel<<<1, 256, 0, stream>>>(sumexp, pos, out);
}

// Round 3
// 263.032 us; speedup vs baseline: 1.4805x; 1.4673x over previous
//
#include <hip/hip_runtime.h>
#include <hip/hip_bf16.h>

// ContrastiveLoss (SimCLR InfoNCE): N=8192, D=1024, T=0.1
// nll[i] = -logit[i, (i+N/2)%N] + logsumexp_j(logit[i,j]), diag masked out
// logit = cos_sim / T; out = mean(nll)
//
// Identities:
//  - logit[i,j] = zn_i . zn_j with zn_i = z_i * sqrt(log2e/T)/||z_i||;
//    then dot d = logit*log2e and exp(logit-10) = 2^(d - 10*log2e) -> raw v_exp_f32.
//  - logit in [-10,10] => FIXED-offset logsumexp (no max tracking); masked diag
//    term is exactly 0, handled only in diagonal blocks (colBase==rowBase).
//  - cross-block logsumexp combine == atomicAdd of partial sum-exp.
//  - positive-pair logit recomputed in finalize as a direct row dot (removes
//    per-value compare/store from the hot epilogue).
//
// R3: explicit double-buffered LDS + cross-phase async prefetch. Phase p+1's
// global_load_lds are issued immediately after the barrier, before computing
// phase p, so compute covers the L2/L3 latency and the compiler's
// vmcnt(0)-before-barrier drain finds the loads already complete. The t x kk
// loops are flattened into one 64-phase loop so prefetch crosses t-seams
// (the epilogue VALU work additionally covers those seams).

#define N_ROWS 8192
#define DIM    1024
#define BM 128
#define BN 128
#define BK 64
#define TCOUNT 4                        // column tiles (of BN) per block
#define KSTEPS (DIM / BK)               // 16
#define NPHASE (KSTEPS * TCOUNT)        // 64
#define LOG2E  1.4426950408889634f
#define OFFS   14.4269504088896340f     // 10 * log2e
#define ROW_SCALE 3.7982825605f         // sqrt(10 * log2e)
#define LN2    0.6931471805599453f
#define LOGIT_MAX 10.0f

typedef __bf16 bf16x8 __attribute__((ext_vector_type(8)));
typedef float floatx4 __attribute__((ext_vector_type(4)));
typedef unsigned short ushort8 __attribute__((ext_vector_type(8)));

__device__ __forceinline__ float bf2f(unsigned short u) {
  union { unsigned u32; float f; } c;
  c.u32 = (unsigned)u << 16;
  return c.f;
}

__device__ __forceinline__ void async_copy16(const __hip_bfloat16* g, void* lds) {
  __builtin_amdgcn_global_load_lds(
      (const __attribute__((address_space(1))) void*)g,
      (__attribute__((address_space(3))) void*)lds, 16, 0, 0);
}

// ---------------- Kernel 1: row normalize (+ zero accumulators) -----------
__global__ __launch_bounds__(256) void normalize_kernel(
    const float* __restrict__ z, __hip_bfloat16* __restrict__ zn,
    float* __restrict__ sumexp, float* __restrict__ out) {
  const int row = blockIdx.x;
  const int tid = threadIdx.x;

  // zero the 8192 sumexp slots (blocks 0..31) and out[0]; stream-ordered
  // before the consumers, so no race
  if (row < (N_ROWS / 256)) sumexp[row * 256 + tid] = 0.0f;
  if (row == 32 && tid == 0) out[0] = 0.0f;

  const float4 v = ((const float4*)(z + (size_t)row * DIM))[tid];
  float ss = v.x * v.x + v.y * v.y + v.z * v.z + v.w * v.w;
  #pragma unroll
  for (int off = 32; off > 0; off >>= 1) ss += __shfl_down(ss, off);
  __shared__ float red[4];
  const int wave = tid >> 6, lane = tid & 63;
  if (lane == 0) red[wave] = ss;
  __syncthreads();
  const float tot = red[0] + red[1] + red[2] + red[3];
  const float scale = rsqrtf(tot) * ROW_SCALE;  // norms ~32 >> eps, eps never binds

  __hip_bfloat16 o[4];
  o[0] = __float2bfloat16(v.x * scale);
  o[1] = __float2bfloat16(v.y * scale);
  o[2] = __float2bfloat16(v.z * scale);
  o[3] = __float2bfloat16(v.w * scale);
  ((uint2*)(zn + (size_t)row * DIM))[tid] = *(const uint2*)o;
}

// ---------------- Kernel 2: fused GEMM + partial sum-exp ------------------
// 256 threads = 4 waves, 2x2 over a 128x128 output tile; each wave 64x64 via
// 4x4 of 16x16x32 bf16 MFMAs. LDS double-buffered 128x64-bf16 tiles with a
// 16B-chunk XOR swizzle applied on the GLOBAL address side (stored chunk c
// holds logical k-chunk c^(r&7)), keeping ds_read_b128 conflict-free while
// satisfying global_load_lds's wave-uniform-base + lane*16 deposit rule.
__global__ __launch_bounds__(256) void fused_gemm_lse(
    const __hip_bfloat16* __restrict__ zn, float* __restrict__ sumexp) {
  __shared__ __hip_bfloat16 sA[2][BM * BK];
  __shared__ __hip_bfloat16 sB[2][BN * BK];

  const int tid  = threadIdx.x;
  const int lane = tid & 63;
  const int wave = tid >> 6;
  const int quad = lane >> 4;
  const int l15  = lane & 15;
  const int waveM = wave >> 1;  // 0..1
  const int waveN = wave & 1;   // 0..1
  const int rowBase  = blockIdx.x * BM;
  const int colChunk = blockIdx.y * (BN * TCOUNT);

  // issue async staging of phase p into buffer b (no wait here)
  auto stage = [&](int b, int p) {
    const int t  = p >> 4;            // p / KSTEPS
    const int kk = (p & 15) * BK;     // (p % KSTEPS) * BK
    const size_t aBase = (size_t)rowBase * DIM;
    const size_t bBase = (size_t)(colChunk + t * BN) * DIM;
    #pragma unroll
    for (int i = 0; i < 4; i++) {
      const int sbase = i * 256 + wave * 64;  // wave-uniform chunk base
      const int s = sbase + lane;
      const int r = s >> 3;                   // tile row 0..127
      const int q = (s & 7) ^ (r & 7);        // logical k-chunk (swizzle)
      const size_t goff = (size_t)r * DIM + kk + q * 8;
      async_copy16(zn + aBase + goff, (char*)sA[b] + sbase * 16);
      async_copy16(zn + bBase + goff, (char*)sB[b] + sbase * 16);
    }
  };

  float l_acc[4][4];
  #pragma unroll
  for (int i = 0; i < 4; i++)
    #pragma unroll
    for (int j = 0; j < 4; j++) l_acc[i][j] = 0.0f;

  floatx4 acc[4][4];
  #pragma unroll
  for (int mi = 0; mi < 4; mi++)
    #pragma unroll
    for (int ni = 0; ni < 4; ni++) acc[mi][ni] = {0.f, 0.f, 0.f, 0.f};

  stage(0, 0);

  for (int p = 0; p < NPHASE; ++p) {
    const int b = p & 1;
    __syncthreads();                 // drains phase p's loads; prev reads done
    if (p + 1 < NPHASE) stage(b ^ 1, p + 1);  // prefetch next phase (async)

    #pragma unroll
    for (int ks = 0; ks < 2; ++ks) {   // two K=32 steps per BK=64
      bf16x8 a[4], bfr[4];
      #pragma unroll
      for (int mi = 0; mi < 4; mi++) {
        const int r = waveM * 64 + mi * 16 + l15;
        const int c = (ks * 4 + quad) ^ (r & 7);
        a[mi] = ((const bf16x8*)sA[b])[r * 8 + c];
      }
      #pragma unroll
      for (int ni = 0; ni < 4; ni++) {
        const int r = waveN * 64 + ni * 16 + l15;
        const int c = (ks * 4 + quad) ^ (r & 7);
        bfr[ni] = ((const bf16x8*)sB[b])[r * 8 + c];
      }
      #pragma unroll
      for (int mi = 0; mi < 4; mi++)
        #pragma unroll
        for (int ni = 0; ni < 4; ni++)
          acc[mi][ni] = __builtin_amdgcn_mfma_f32_16x16x32_bf16(
              a[mi], bfr[ni], acc[mi][ni], 0, 0, 0);
    }

    if ((p & 15) == 15) {
      // epilogue for t = p>>4 — runs while phase p+1's loads are in flight.
      // C/D layout (16x16): col = lane&15, row = quad*4 + reg  [m89]
      const int colBase = colChunk + (p >> 4) * BN;
      const bool diag = (colBase == rowBase);  // wave-uniform
      if (diag) {
        #pragma unroll
        for (int mi = 0; mi < 4; mi++)
          #pragma unroll
          for (int r = 0; r < 4; r++) {
            const int lrow = waveM * 64 + mi * 16 + quad * 4 + r;
            float sum = 0.f;
            #pragma unroll
            for (int ni = 0; ni < 4; ni++) {
              const int lcol = waveN * 64 + ni * 16 + l15;
              float e = __builtin_expf(LN2 * 0.f), d = acc[mi][ni][r] - OFFS;
              e = exp2f(d);
              if (lcol == lrow) e = 0.f;   // masked diagonal
              sum += e;
            }
            l_acc[mi][r] += sum;
          }
      } else {
        #pragma unroll
        for (int mi = 0; mi < 4; mi++)
          #pragma unroll
          for (int r = 0; r < 4; r++) {
            float sum = 0.f;
            #pragma unroll
            for (int ni = 0; ni < 4; ni++)
              sum += exp2f(acc[mi][ni][r] - OFFS);
            l_acc[mi][r] += sum;
          }
      }
      #pragma unroll
      for (int mi = 0; mi < 4; mi++)
        #pragma unroll
        for (int ni = 0; ni < 4; ni++) acc[mi][ni] = {0.f, 0.f, 0.f, 0.f};
    }
  }

  // reduce partial sum-exp across the 16 lanes sharing each row, then one
  // atomicAdd per (row, block)
  #pragma unroll
  for (int mi = 0; mi < 4; mi++)
    #pragma unroll
    for (int r = 0; r < 4; r++) {
      float v = l_acc[mi][r];
      v += __shfl_xor(v, 1);
      v += __shfl_xor(v, 2);
      v += __shfl_xor(v, 4);
      v += __shfl_xor(v, 8);
      if (l15 == 0) {
        const int grow = rowBase + waveM * 64 + mi * 16 + quad * 4 + r;
        atomicAdd(&sumexp[grow], v);
      }
    }
}

// ---------------- Kernel 3: positive-pair dots + mean NLL -----------------
// 64 blocks x 4 waves; each wave handles 32 rows. Per row: dot(zn[row],
// zn[row+N/2]) across 64 lanes (16 elems/lane), shuffle-reduce, accumulate
// nll; block partial atomically added into out[0] (pre-divided by N).
__global__ __launch_bounds__(256) void finalize_kernel(
    const __hip_bfloat16* __restrict__ zn, const float* __restrict__ sumexp,
    float* __restrict__ out) {
  const int tid = threadIdx.x, wave = tid >> 6, lane = tid & 63;
  float local = 0.0f;
  for (int i = 0; i < 32; ++i) {
    const int row  = blockIdx.x * 128 + wave * 32 + i;
    const int prow = (row + N_ROWS / 2) & (N_ROWS - 1);
    const ushort8* a = (const ushort8*)(zn + (size_t)row  * DIM);
    const ushort8* b = (const ushort8*)(zn + (size_t)prow * DIM);
    float d = 0.0f;
    #pragma unroll
    for (int j = 0; j < 2; ++j) {
      const ushort8 av = a[lane * 2 + j];
      const ushort8 bv = b[lane * 2 + j];
      #pragma unroll
      for (int e = 0; e < 8; ++e) d += bf2f(av[e]) * bf2f(bv[e]);
    }
    #pragma unroll
    for (int off = 32; off > 0; off >>= 1) d += __shfl_xor(d, off);
    if (lane == 0) {
      // d = logit * log2e  ->  pos logit = d * ln2
      local += -(d * LN2) + LOGIT_MAX + logf(sumexp[row]);
    }
  }
  __shared__ float red[4];
  if (lane == 0) red[wave] = local;
  __syncthreads();
  if (tid == 0)
    atomicAdd(out, (red[0] + red[1] + red[2] + red[3]) * (1.0f / N_ROWS));
}

extern "C" void kernel_launch(void* const* d_in, const int* in_sizes, int n_in,
                              void* d_out, int out_size, void* d_ws, size_t ws_size,
                              hipStream_t stream) {
  const float* z = (const float*)d_in[0];
  float* out = (float*)d_out;

  char* ws = (char*)d_ws;
  __hip_bfloat16* zn = (__hip_bfloat16*)ws;                  // 16 MB
  float* sumexp = (float*)(ws + (size_t)N_ROWS * DIM * 2);   // 32 KB

  normalize_kernel<<<N_ROWS, 256, 0, stream>>>(z, zn, sumexp, out);
  fused_gemm_lse<<<dim3(N_ROWS / BM, N_ROWS / (BN * TCOUNT)), 256, 0, stream>>>(
      zn, sumexp);
  finalize_kernel<<<64, 256, 0, stream>>>(zn, sumexp, out);
}

// Round 4
// 187.549 us; speedup vs baseline: 2.0763x; 1.4025x over previous
//
#include <hip/hip_runtime.h>
#include <hip/hip_bf16.h>

// ContrastiveLoss (SimCLR InfoNCE): N=8192, D=1024, T=0.1
// nll[i] = -logit[i, (i+N/2)%N] + logsumexp_j(logit[i,j]), diag masked out
// logit = cos_sim / T; out = mean(nll)
//
// Identities:
//  - zn_i = z_i * sqrt(log2e/T)/||z_i||  =>  dot d = logit*log2e and
//    exp(logit-10) = 2^(d - 10*log2e)  -> raw v_exp_f32.
//  - logit in [-10,10] => FIXED-offset logsumexp (no max tracking); masked
//    diagonal term is exactly 0, handled only in the 64 diagonal supertiles.
//  - Gram matrix is SYMMETRIC: compute only upper-triangular 128x128
//    supertiles (2080 of 4096). Off-diagonal tile (I,J) contributes its
//    exp row-sums to rows of I and its exp col-sums to rows of J.
//  - positive-pair logits are the tile diagonals of blocks (I, I+32),
//    I<32 (pos[i+4096] == pos[i]) — extracted in-epilogue, no extra GEMM.
//  - cross-block logsumexp combine == atomicAdd of partial sum-exp
//    (LDS-combined to 1 atomic per row / col per block).
//
// R4: symmetry (halves MFMA work) + in-epilogue pos extraction + fatter
// normalize/finalize. Keeps R3's double-buffered LDS + cross-phase
// global_load_lds prefetch and the global-side XOR swizzle (stored chunk c
// holds logical k-chunk c^(r&7)) for conflict-free ds_read_b128.

#define N_ROWS 8192
#define DIM    1024
#define BM 128
#define BK 64
#define NPHASE (DIM / BK)               // 16
#define LOG2E  1.4426950408889634f
#define OFFS   14.4269504088896340f     // 10 * log2e
#define ROW_SCALE 3.7982825605f         // sqrt(10 * log2e)
#define LN2    0.6931471805599453f
#define LOGIT_MAX 10.0f

typedef __bf16 bf16x8 __attribute__((ext_vector_type(8)));
typedef float floatx4 __attribute__((ext_vector_type(4)));

__device__ __forceinline__ void async_copy16(const __hip_bfloat16* g, void* lds) {
  __builtin_amdgcn_global_load_lds(
      (const __attribute__((address_space(1))) void*)g,
      (__attribute__((address_space(3))) void*)lds, 16, 0, 0);
}

// ---------------- Kernel 1: row normalize (+ zero accumulators) -----------
// One wave per row (4 rows/block), no LDS, no barriers.
__global__ __launch_bounds__(256) void normalize_kernel(
    const float* __restrict__ z, __hip_bfloat16* __restrict__ zn,
    float* __restrict__ sumexp, float* __restrict__ out) {
  const int tid = threadIdx.x, wave = tid >> 6, lane = tid & 63;
  const int row = blockIdx.x * 4 + wave;

  // zero sumexp (blocks 0..7) and out (block 8); stream-ordered before use
  if (blockIdx.x < 8) ((float4*)sumexp)[blockIdx.x * 256 + tid] = float4{0, 0, 0, 0};
  if (blockIdx.x == 8 && tid == 0) out[0] = 0.0f;

  const float4* zr = (const float4*)(z + (size_t)row * DIM);
  float4 v[4];
  #pragma unroll
  for (int j = 0; j < 4; j++) v[j] = zr[lane + 64 * j];
  float ss = 0.0f;
  #pragma unroll
  for (int j = 0; j < 4; j++)
    ss += v[j].x * v[j].x + v[j].y * v[j].y + v[j].z * v[j].z + v[j].w * v[j].w;
  #pragma unroll
  for (int off = 32; off > 0; off >>= 1) ss += __shfl_xor(ss, off);
  const float scale = rsqrtf(ss) * ROW_SCALE;  // norms ~32 >> eps, eps never binds

  uint2* o = (uint2*)(zn + (size_t)row * DIM);
  #pragma unroll
  for (int j = 0; j < 4; j++) {
    __hip_bfloat16 ob[4];
    ob[0] = __float2bfloat16(v[j].x * scale);
    ob[1] = __float2bfloat16(v[j].y * scale);
    ob[2] = __float2bfloat16(v[j].z * scale);
    ob[3] = __float2bfloat16(v[j].w * scale);
    o[lane + 64 * j] = *(const uint2*)ob;
  }
}

// ---------------- Kernel 2: upper-tri GEMM + partial sum-exp --------------
// 2080 blocks, one 128x128 supertile (I<=J) each. 4 waves 2x2; each wave
// 64x64 via 4x4 of 16x16x32 bf16 MFMAs. Double-buffered LDS, cross-phase
// async prefetch, running staging pointers (+BK/phase).
__global__ __launch_bounds__(256) void fused_gemm_lse(
    const __hip_bfloat16* __restrict__ zn, float* __restrict__ sumexp,
    float* __restrict__ pos) {
  __shared__ __hip_bfloat16 sA[2][BM * BK];
  __shared__ __hip_bfloat16 sB[2][BM * BK];
  __shared__ float rowRed[2][BM];
  __shared__ float colRed[2][BM];

  const int tid  = threadIdx.x;
  const int lane = tid & 63;
  const int wave = tid >> 6;
  const int quad = lane >> 4;
  const int l15  = lane & 15;
  const int waveM = wave >> 1;  // 0..1
  const int waveN = wave & 1;   // 0..1

  // decode upper-triangular supertile (I, J), I<=J<64, from blockIdx.x
  // row I starts at C(I) = I*(129-I)/2
  const int bid = blockIdx.x;
  int I = (int)(64.5f - sqrtf(64.5f * 64.5f - 2.0f * (float)bid));
  while ((I + 1) * (129 - (I + 1)) / 2 <= bid) ++I;
  while (I * (129 - I) / 2 > bid) --I;
  const int J = I + (bid - I * (129 - I) / 2);
  const int rowBase = I * BM, colBase = J * BM;

  // per-thread staging state: 4 chunks each for A and B; advance +BK/phase
  const __hip_bfloat16* aP[4];
  const __hip_bfloat16* bP[4];
  int ldsOff[4];
  #pragma unroll
  for (int i = 0; i < 4; i++) {
    const int sbase = i * 256 + wave * 64;  // wave-uniform chunk base
    const int s = sbase + lane;
    const int r = s >> 3;                   // tile row 0..127
    const int q = (s & 7) ^ (r & 7);        // logical k-chunk (XOR swizzle)
    aP[i] = zn + (size_t)(rowBase + r) * DIM + q * 8;
    bP[i] = zn + (size_t)(colBase + r) * DIM + q * 8;
    ldsOff[i] = sbase * 16;
  }
  auto stage = [&](int b) {
    char* baseA = (char*)sA + b * (BM * BK * 2);
    char* baseB = (char*)sB + b * (BM * BK * 2);
    #pragma unroll
    for (int i = 0; i < 4; i++) {
      async_copy16(aP[i], baseA + ldsOff[i]);
      async_copy16(bP[i], baseB + ldsOff[i]);
      aP[i] += BK;
      bP[i] += BK;
    }
  };

  floatx4 acc[4][4];
  #pragma unroll
  for (int mi = 0; mi < 4; mi++)
    #pragma unroll
    for (int ni = 0; ni < 4; ni++) acc[mi][ni] = {0.f, 0.f, 0.f, 0.f};

  stage(0);

  for (int p = 0; p < NPHASE; ++p) {
    const int b = p & 1;
    __syncthreads();                 // drains phase p's loads; prev reads done
    if (p + 1 < NPHASE) stage(b ^ 1);  // prefetch next phase (async)

    #pragma unroll
    for (int ks = 0; ks < 2; ++ks) {   // two K=32 steps per BK=64
      bf16x8 a[4], bfr[4];
      #pragma unroll
      for (int mi = 0; mi < 4; mi++) {
        const int r = waveM * 64 + mi * 16 + l15;
        const int c = (ks * 4 + quad) ^ (r & 7);
        a[mi] = ((const bf16x8*)sA[b])[r * 8 + c];
      }
      #pragma unroll
      for (int ni = 0; ni < 4; ni++) {
        const int r = waveN * 64 + ni * 16 + l15;
        const int c = (ks * 4 + quad) ^ (r & 7);
        bfr[ni] = ((const bf16x8*)sB[b])[r * 8 + c];
      }
      #pragma unroll
      for (int mi = 0; mi < 4; mi++)
        #pragma unroll
        for (int ni = 0; ni < 4; ni++)
          acc[mi][ni] = __builtin_amdgcn_mfma_f32_16x16x32_bf16(
              a[mi], bfr[ni], acc[mi][ni], 0, 0, 0);
    }
  }

  // ---- epilogue ----
  // C/D layout (16x16): col = lane&15, row = quad*4 + reg  [m89]
  // local row = waveM*64 + mi*16 + quad*4 + r ; local col = waveN*64 + ni*16 + l15
  const bool diagBlk = (I == J);
  const bool posBlk  = (J == I + 32);  // tile diagonal == positive pairs

  if (posBlk && waveM == waveN) {
    #pragma unroll
    for (int mi = 0; mi < 4; mi++)
      #pragma unroll
      for (int r = 0; r < 4; r++)
        if (l15 == quad * 4 + r)
          pos[rowBase + waveM * 64 + mi * 16 + l15] = acc[mi][mi][r];
  }

  float rsum[4][4], csum[4];
  #pragma unroll
  for (int mi = 0; mi < 4; mi++)
    #pragma unroll
    for (int r = 0; r < 4; r++) rsum[mi][r] = 0.0f;
  #pragma unroll
  for (int ni = 0; ni < 4; ni++) csum[ni] = 0.0f;

  if (diagBlk) {
    #pragma unroll
    for (int mi = 0; mi < 4; mi++)
      #pragma unroll
      for (int ni = 0; ni < 4; ni++)
        #pragma unroll
        for (int r = 0; r < 4; r++) {
          const int lrow = waveM * 64 + mi * 16 + quad * 4 + r;
          const int lcol = waveN * 64 + ni * 16 + l15;
          float e = exp2f(acc[mi][ni][r] - OFFS);
          if (lcol == lrow) e = 0.0f;   // masked diagonal
          rsum[mi][r] += e;
        }
  } else {
    #pragma unroll
    for (int mi = 0; mi < 4; mi++)
      #pragma unroll
      for (int ni = 0; ni < 4; ni++)
        #pragma unroll
        for (int r = 0; r < 4; r++) {
          const float e = exp2f(acc[mi][ni][r] - OFFS);
          rsum[mi][r] += e;
          csum[ni]    += e;
        }
  }

  // row partials: reduce over the 16 lanes (l15) sharing each row
  #pragma unroll
  for (int mi = 0; mi < 4; mi++)
    #pragma unroll
    for (int r = 0; r < 4; r++) {
      float v = rsum[mi][r];
      v += __shfl_xor(v, 1);
      v += __shfl_xor(v, 2);
      v += __shfl_xor(v, 4);
      v += __shfl_xor(v, 8);
      if (l15 == 0)
        rowRed[waveN][waveM * 64 + mi * 16 + quad * 4 + r] = v;
    }
  // col partials: reduce over the 4 quads sharing each col
  if (!diagBlk) {
    #pragma unroll
    for (int ni = 0; ni < 4; ni++) {
      float v = csum[ni];
      v += __shfl_xor(v, 16);
      v += __shfl_xor(v, 32);
      if (quad == 0)
        colRed[waveM][waveN * 64 + ni * 16 + l15] = v;
    }
  }
  __syncthreads();

  if (tid < BM) {
    atomicAdd(&sumexp[rowBase + tid], rowRed[0][tid] + rowRed[1][tid]);
  } else if (!diagBlk) {
    const int c = tid - BM;
    atomicAdd(&sumexp[colBase + c], colRed[0][c] + colRed[1][c]);
  }
}

// ---------------- Kernel 3: mean NLL --------------------------------------
__global__ __launch_bounds__(256) void finalize_kernel(
    const float* __restrict__ sumexp, const float* __restrict__ pos,
    float* __restrict__ out) {
  const int tid = threadIdx.x;
  const int row = blockIdx.x * 256 + tid;
  // pos holds d = logit*log2e for rows [0,4096); pos[i+4096] == pos[i]
  float local = -(pos[row & (N_ROWS / 2 - 1)] * LN2) + LOGIT_MAX + logf(sumexp[row]);
  #pragma unroll
  for (int off = 32; off > 0; off >>= 1) local += __shfl_xor(local, off);
  __shared__ float red[4];
  const int wave = tid >> 6, lane = tid & 63;
  if (lane == 0) red[wave] = local;
  __syncthreads();
  if (tid == 0)
    atomicAdd(out, (red[0] + red[1] + red[2] + red[3]) * (1.0f / N_ROWS));
}

extern "C" void kernel_launch(void* const* d_in, const int* in_sizes, int n_in,
                              void* d_out, int out_size, void* d_ws, size_t ws_size,
                              hipStream_t stream) {
  const float* z = (const float*)d_in[0];
  float* out = (float*)d_out;

  char* ws = (char*)d_ws;
  __hip_bfloat16* zn = (__hip_bfloat16*)ws;                  // 16 MB
  float* sumexp = (float*)(ws + (size_t)N_ROWS * DIM * 2);   // 32 KB
  float* pos    = sumexp + N_ROWS;                           // 16 KB (4096)

  normalize_kernel<<<N_ROWS / 4, 256, 0, stream>>>(z, zn, sumexp, out);
  fused_gemm_lse<<<64 * 65 / 2, 256, 0, stream>>>(zn, sumexp, pos);
  finalize_kernel<<<N_ROWS / 256, 256, 0, stream>>>(sumexp, pos, out);
}